// Round 1
// baseline (2935.262 us; speedup 1.0000x reference)
//
#include <hip/hip_runtime.h>

#define NN 50000
#define NE 800000
#define D 128
#define BM 32

// ---- degree: one atomic per edge ----
__global__ void k_deg(const int* __restrict__ dst, float* __restrict__ deg, int E) {
    int e = blockIdx.x * blockDim.x + threadIdx.x;
    if (e < E) atomicAdd(&deg[dst[e]], 1.0f);
}

// ---- scatter-add: 32 threads per edge, float4 gather + 4 scalar atomics ----
__global__ void k_scatter(const float* __restrict__ h, const int* __restrict__ src,
                          const int* __restrict__ dst, float* __restrict__ agg, int E) {
    int t = blockIdx.x * blockDim.x + threadIdx.x;
    int e = t >> 5;
    if (e >= E) return;
    int p = t & 31;
    int s = src[e];
    int d = dst[e];
    const float4 v = *reinterpret_cast<const float4*>(h + (size_t)s * D + p * 4);
    float* a = agg + (size_t)d * D + p * 4;
    atomicAdd(a + 0, v.x);
    atomicAdd(a + 1, v.y);
    atomicAdd(a + 2, v.z);
    atomicAdd(a + 3, v.w);
}

// ---- fused SAGE layer: out = relu(h @ Wself + (agg/deg) @ Wneigh + b) ----
// BM=32 rows per block, 256 threads: thread = (rh in {0,1}) x (col in [0,128))
// each thread computes 16 rows of one column. h/hn tiles staged in LDS.
__global__ __launch_bounds__(256) void k_gemm(
    const float* __restrict__ h, const float* __restrict__ agg, const float* __restrict__ deg,
    const float* __restrict__ Wself, const float* __restrict__ Wneigh,
    const float* __restrict__ bias, float* __restrict__ out, int n)
{
    __shared__ float hs[BM][D];
    __shared__ float hn[BM][D];
    const int row0 = blockIdx.x * BM;
    const int tid = threadIdx.x;

    // stage tiles: 32 rows x 128 cols = 1024 float4 total, 4 per thread
    #pragma unroll
    for (int i = 0; i < 4; ++i) {
        int f = tid + i * 256;     // float4 index in tile
        int r = f >> 5;            // 32 float4 per row
        int c4 = f & 31;
        int g = row0 + r;
        float4 v = make_float4(0.f, 0.f, 0.f, 0.f);
        float4 a = make_float4(0.f, 0.f, 0.f, 0.f);
        float invd = 0.f;
        if (g < n) {
            v = *reinterpret_cast<const float4*>(h + (size_t)g * D + c4 * 4);
            a = *reinterpret_cast<const float4*>(agg + (size_t)g * D + c4 * 4);
            invd = 1.0f / fmaxf(deg[g], 1.0f);
        }
        *reinterpret_cast<float4*>(&hs[r][c4 * 4]) = v;
        a.x *= invd; a.y *= invd; a.z *= invd; a.w *= invd;
        *reinterpret_cast<float4*>(&hn[r][c4 * 4]) = a;
    }
    __syncthreads();

    const int col = tid & 127;
    const int rh = tid >> 7;   // 0 or 1: which 16-row half
    float acc[16];
    #pragma unroll
    for (int r = 0; r < 16; ++r) acc[r] = 0.f;

    #pragma unroll 1
    for (int k4 = 0; k4 < 32; ++k4) {
        const int k = k4 * 4;
        const float ws0 = Wself[(k + 0) * D + col];
        const float ws1 = Wself[(k + 1) * D + col];
        const float ws2 = Wself[(k + 2) * D + col];
        const float ws3 = Wself[(k + 3) * D + col];
        const float wn0 = Wneigh[(k + 0) * D + col];
        const float wn1 = Wneigh[(k + 1) * D + col];
        const float wn2 = Wneigh[(k + 2) * D + col];
        const float wn3 = Wneigh[(k + 3) * D + col];
        #pragma unroll
        for (int r = 0; r < 16; ++r) {
            const float4 hv = *reinterpret_cast<const float4*>(&hs[rh * 16 + r][k]);
            const float4 nv = *reinterpret_cast<const float4*>(&hn[rh * 16 + r][k]);
            float t0 = fmaf(hv.x, ws0, acc[r]);
            t0 = fmaf(hv.y, ws1, t0);
            t0 = fmaf(hv.z, ws2, t0);
            t0 = fmaf(hv.w, ws3, t0);
            t0 = fmaf(nv.x, wn0, t0);
            t0 = fmaf(nv.y, wn1, t0);
            t0 = fmaf(nv.z, wn2, t0);
            t0 = fmaf(nv.w, wn3, t0);
            acc[r] = t0;
        }
    }

    const float bj = bias[col];
    #pragma unroll
    for (int r = 0; r < 16; ++r) {
        const int g = row0 + rh * 16 + r;
        if (g < n) out[(size_t)g * D + col] = fmaxf(acc[r] + bj, 0.f);
    }
}

// ---- row L2 normalize: one wave per row, float2 per lane ----
__global__ void k_norm(float* __restrict__ out, int n) {
    const int gtid = blockIdx.x * blockDim.x + threadIdx.x;
    const int row = gtid >> 6;
    const int lane = threadIdx.x & 63;
    if (row >= n) return;
    float2 v = *reinterpret_cast<float2*>(out + (size_t)row * D + lane * 2);
    float ssq = v.x * v.x + v.y * v.y;
    #pragma unroll
    for (int o = 32; o >= 1; o >>= 1) ssq += __shfl_xor(ssq, o);
    const float scale = 1.0f / fmaxf(sqrtf(ssq), 1e-12f);
    v.x *= scale; v.y *= scale;
    *reinterpret_cast<float2*>(out + (size_t)row * D + lane * 2) = v;
}

extern "C" void kernel_launch(void* const* d_in, const int* in_sizes, int n_in,
                              void* d_out, int out_size, void* d_ws, size_t ws_size,
                              hipStream_t stream) {
    const float* x   = (const float*)d_in[0];
    const int*   src = (const int*)d_in[1];
    const int*   dst = (const int*)d_in[2];
    const float* Ws0 = (const float*)d_in[3];
    const float* Wn0 = (const float*)d_in[4];
    const float* b0  = (const float*)d_in[5];
    const float* Ws1 = (const float*)d_in[6];
    const float* Wn1 = (const float*)d_in[7];
    const float* b1  = (const float*)d_in[8];
    float* out = (float*)d_out;

    float* agg = (float*)d_ws;                       // NN*D floats = 25.6 MB
    float* deg = agg + (size_t)NN * D;               // NN floats

    const size_t aggBytes = (size_t)NN * D * sizeof(float);

    hipMemsetAsync(agg, 0, aggBytes, stream);
    hipMemsetAsync(deg, 0, (size_t)NN * sizeof(float), stream);

    k_deg<<<(NE + 255) / 256, 256, 0, stream>>>(dst, deg, NE);

    // ---- layer 1 ----
    k_scatter<<<(NE * 32 + 255) / 256, 256, 0, stream>>>(x, src, dst, agg, NE);
    k_gemm<<<(NN + BM - 1) / BM, 256, 0, stream>>>(x, agg, deg, Ws0, Wn0, b0, out, NN);

    // ---- layer 2 (h1 lives in d_out; gemm stages its rows to LDS before overwrite) ----
    hipMemsetAsync(agg, 0, aggBytes, stream);
    k_scatter<<<(NE * 32 + 255) / 256, 256, 0, stream>>>(out, src, dst, agg, NE);
    k_gemm<<<(NN + BM - 1) / BM, 256, 0, stream>>>(out, agg, deg, Ws1, Wn1, b1, out, NN);

    // ---- final row normalize ----
    k_norm<<<(NN * 64 + 255) / 256, 256, 0, stream>>>(out, NN);
}

// Round 2
// 495.512 us; speedup vs baseline: 5.9237x; 5.9237x over previous
//
#include <hip/hip_runtime.h>

#define NN 50000
#define NE 800000
#define D 128
#define BM 32

// ---- in-degree histogram: one int atomic per edge ----
__global__ void k_hist(const int* __restrict__ dst, int* __restrict__ hist, int E) {
    int e = blockIdx.x * blockDim.x + threadIdx.x;
    if (e < E) atomicAdd(&hist[dst[e]], 1);
}

// ---- single-block exclusive scan over NN counts -> row_off[NN+1], cursor copy ----
__global__ __launch_bounds__(1024) void k_scan(const int* __restrict__ hist,
        int* __restrict__ row_off, int* __restrict__ cursor, int n) {
    const int t = threadIdx.x;
    const int C = (n + 1023) / 1024;
    const int i0 = t * C;
    const int i1 = min(i0 + C, n);
    int s = 0;
    for (int i = i0; i < i1; ++i) s += hist[i];
    const int lane = t & 63, w = t >> 6;
    int inc = s;
    #pragma unroll
    for (int o = 1; o < 64; o <<= 1) {
        int v = __shfl_up(inc, o);
        if (lane >= o) inc += v;
    }
    __shared__ int wsum[16], woff[16];
    if (lane == 63) wsum[w] = inc;
    __syncthreads();
    if (t == 0) { int r = 0; for (int k = 0; k < 16; ++k) { woff[k] = r; r += wsum[k]; } }
    __syncthreads();
    int run = woff[w] + (inc - s);   // exclusive prefix for this thread
    for (int i = i0; i < i1; ++i) {
        row_off[i] = run; cursor[i] = run; run += hist[i];
    }
    if (i0 < n && i1 == n) row_off[n] = run;   // total = NE
}

// ---- CSR fill: pos = cursor[dst]++, csr_src[pos] = src ----
__global__ void k_fill(const int* __restrict__ src, const int* __restrict__ dst,
                       int* __restrict__ cursor, int* __restrict__ csr, int E) {
    int e = blockIdx.x * blockDim.x + threadIdx.x;
    if (e < E) {
        int p = atomicAdd(&cursor[dst[e]], 1);
        csr[p] = src[e];
    }
}

// ---- pull-mean aggregation: one wave per dst node, lane = float2 of the row ----
__global__ void k_pull(const float* __restrict__ h, const int* __restrict__ csr,
                       const int* __restrict__ row_off, float* __restrict__ agg, int n) {
    const int w = blockIdx.x * 4 + (threadIdx.x >> 6);
    if (w >= n) return;
    const int lane = threadIdx.x & 63;
    const int beg = row_off[w], end = row_off[w + 1];
    float2 a0 = make_float2(0.f, 0.f), a1 = make_float2(0.f, 0.f);
    int i = beg;
    for (; i + 1 < end; i += 2) {
        int s0 = csr[i], s1 = csr[i + 1];
        float2 v0 = *reinterpret_cast<const float2*>(h + (size_t)s0 * D + lane * 2);
        float2 v1 = *reinterpret_cast<const float2*>(h + (size_t)s1 * D + lane * 2);
        a0.x += v0.x; a0.y += v0.y;
        a1.x += v1.x; a1.y += v1.y;
    }
    if (i < end) {
        int s0 = csr[i];
        float2 v0 = *reinterpret_cast<const float2*>(h + (size_t)s0 * D + lane * 2);
        a0.x += v0.x; a0.y += v0.y;
    }
    const float invd = (end > beg) ? 1.0f / (float)(end - beg) : 0.0f;
    float2 r;
    r.x = (a0.x + a1.x) * invd;
    r.y = (a0.y + a1.y) * invd;
    *reinterpret_cast<float2*>(agg + (size_t)w * D + lane * 2) = r;
}

// ---- fused SAGE layer: out = relu(h @ Wself + hn @ Wneigh + b), hn pre-averaged ----
__global__ __launch_bounds__(256) void k_gemm(
    const float* __restrict__ h, const float* __restrict__ hneigh,
    const float* __restrict__ Wself, const float* __restrict__ Wneigh,
    const float* __restrict__ bias, float* __restrict__ out, int n)
{
    __shared__ float hs[BM][D];
    __shared__ float hn[BM][D];
    const int row0 = blockIdx.x * BM;
    const int tid = threadIdx.x;

    #pragma unroll
    for (int i = 0; i < 4; ++i) {
        int f = tid + i * 256;
        int r = f >> 5;
        int c4 = f & 31;
        int g = row0 + r;
        float4 v = make_float4(0.f, 0.f, 0.f, 0.f);
        float4 a = make_float4(0.f, 0.f, 0.f, 0.f);
        if (g < n) {
            v = *reinterpret_cast<const float4*>(h + (size_t)g * D + c4 * 4);
            a = *reinterpret_cast<const float4*>(hneigh + (size_t)g * D + c4 * 4);
        }
        *reinterpret_cast<float4*>(&hs[r][c4 * 4]) = v;
        *reinterpret_cast<float4*>(&hn[r][c4 * 4]) = a;
    }
    __syncthreads();

    const int col = tid & 127;
    const int rh = tid >> 7;
    float acc[16];
    #pragma unroll
    for (int r = 0; r < 16; ++r) acc[r] = 0.f;

    #pragma unroll 1
    for (int k4 = 0; k4 < 32; ++k4) {
        const int k = k4 * 4;
        const float ws0 = Wself[(k + 0) * D + col];
        const float ws1 = Wself[(k + 1) * D + col];
        const float ws2 = Wself[(k + 2) * D + col];
        const float ws3 = Wself[(k + 3) * D + col];
        const float wn0 = Wneigh[(k + 0) * D + col];
        const float wn1 = Wneigh[(k + 1) * D + col];
        const float wn2 = Wneigh[(k + 2) * D + col];
        const float wn3 = Wneigh[(k + 3) * D + col];
        #pragma unroll
        for (int r = 0; r < 16; ++r) {
            const float4 hv = *reinterpret_cast<const float4*>(&hs[rh * 16 + r][k]);
            const float4 nv = *reinterpret_cast<const float4*>(&hn[rh * 16 + r][k]);
            float t0 = fmaf(hv.x, ws0, acc[r]);
            t0 = fmaf(hv.y, ws1, t0);
            t0 = fmaf(hv.z, ws2, t0);
            t0 = fmaf(hv.w, ws3, t0);
            t0 = fmaf(nv.x, wn0, t0);
            t0 = fmaf(nv.y, wn1, t0);
            t0 = fmaf(nv.z, wn2, t0);
            t0 = fmaf(nv.w, wn3, t0);
            acc[r] = t0;
        }
    }

    const float bj = bias[col];
    #pragma unroll
    for (int r = 0; r < 16; ++r) {
        const int g = row0 + rh * 16 + r;
        if (g < n) out[(size_t)g * D + col] = fmaxf(acc[r] + bj, 0.f);
    }
}

// ---- row L2 normalize: one wave per row ----
__global__ void k_norm(float* __restrict__ out, int n) {
    const int gtid = blockIdx.x * blockDim.x + threadIdx.x;
    const int row = gtid >> 6;
    const int lane = threadIdx.x & 63;
    if (row >= n) return;
    float2 v = *reinterpret_cast<float2*>(out + (size_t)row * D + lane * 2);
    float ssq = v.x * v.x + v.y * v.y;
    #pragma unroll
    for (int o = 32; o >= 1; o >>= 1) ssq += __shfl_xor(ssq, o);
    const float scale = 1.0f / fmaxf(sqrtf(ssq), 1e-12f);
    v.x *= scale; v.y *= scale;
    *reinterpret_cast<float2*>(out + (size_t)row * D + lane * 2) = v;
}

extern "C" void kernel_launch(void* const* d_in, const int* in_sizes, int n_in,
                              void* d_out, int out_size, void* d_ws, size_t ws_size,
                              hipStream_t stream) {
    const float* x   = (const float*)d_in[0];
    const int*   src = (const int*)d_in[1];
    const int*   dst = (const int*)d_in[2];
    const float* Ws0 = (const float*)d_in[3];
    const float* Wn0 = (const float*)d_in[4];
    const float* b0  = (const float*)d_in[5];
    const float* Ws1 = (const float*)d_in[6];
    const float* Wn1 = (const float*)d_in[7];
    const float* b1  = (const float*)d_in[8];
    float* out = (float*)d_out;

    // workspace layout
    float* agg     = (float*)d_ws;                       // NN*D floats = 25.6 MB
    int*   hist    = (int*)(agg + (size_t)NN * D);       // NN
    int*   row_off = hist + NN;                          // NN+1
    int*   cursor  = row_off + NN + 1;                   // NN
    int*   csr     = cursor + NN;                        // NE = 3.2 MB

    // ---- build CSR (deterministic work; fill order nondeterministic but fp-safe) ----
    hipMemsetAsync(hist, 0, (size_t)NN * sizeof(int), stream);
    k_hist<<<(NE + 255) / 256, 256, 0, stream>>>(dst, hist, NE);
    k_scan<<<1, 1024, 0, stream>>>(hist, row_off, cursor, NN);
    k_fill<<<(NE + 255) / 256, 256, 0, stream>>>(src, dst, cursor, csr, NE);

    // ---- layer 1 ----
    k_pull<<<(NN + 3) / 4, 256, 0, stream>>>(x, csr, row_off, agg, NN);
    k_gemm<<<(NN + BM - 1) / BM, 256, 0, stream>>>(x, agg, Ws0, Wn0, b0, out, NN);

    // ---- layer 2 (in-place on d_out: each gemm block reads only its own rows) ----
    k_pull<<<(NN + 3) / 4, 256, 0, stream>>>(out, csr, row_off, agg, NN);
    k_gemm<<<(NN + BM - 1) / BM, 256, 0, stream>>>(out, agg, Ws1, Wn1, b1, out, NN);

    // ---- final row normalize ----
    k_norm<<<(NN * 64 + 255) / 256, 256, 0, stream>>>(out, NN);
}

// Round 4
// 441.009 us; speedup vs baseline: 6.6558x; 1.1236x over previous
//
#include <hip/hip_runtime.h>

#define NN 50000
#define D 128
#define BM 32

// ---- in-degree histogram: one int atomic per edge ----
__global__ void k_hist(const int* __restrict__ dst, int* __restrict__ hist, int E) {
    int e = blockIdx.x * blockDim.x + threadIdx.x;
    if (e < E) atomicAdd(&hist[dst[e]], 1);
}

// ---- scan phase A: per-block (512 elems) partial sums ----
__global__ __launch_bounds__(256) void k_bsum(const int* __restrict__ hist,
                                              int* __restrict__ bsum, int n) {
    const int t = threadIdx.x;
    const int i0 = blockIdx.x * 512 + t * 2;
    int s = 0;
    if (i0 < n) s += hist[i0];
    if (i0 + 1 < n) s += hist[i0 + 1];
    #pragma unroll
    for (int o = 1; o < 64; o <<= 1) s += __shfl_xor(s, o);
    __shared__ int wsum[4];
    if ((t & 63) == 0) wsum[t >> 6] = s;
    __syncthreads();
    if (t == 0) bsum[blockIdx.x] = wsum[0] + wsum[1] + wsum[2] + wsum[3];
}

// ---- scan phase B: exclusive scan of <=128 block sums, one block ----
__global__ __launch_bounds__(128) void k_bscan(int* __restrict__ bsum, int nb) {
    const int t = threadIdx.x;
    const int lane = t & 63, w = t >> 6;
    int v = (t < nb) ? bsum[t] : 0;
    int inc = v;
    #pragma unroll
    for (int o = 1; o < 64; o <<= 1) { int u = __shfl_up(inc, o); if (lane >= o) inc += u; }
    __shared__ int wsum[2];
    if (lane == 63) wsum[w] = inc;
    __syncthreads();
    int off = (w == 1) ? wsum[0] : 0;
    if (t < nb) bsum[t] = off + inc - v;   // exclusive
}

// ---- scan phase C: in-block exclusive scan + block offset -> row_off, cursor ----
__global__ __launch_bounds__(256) void k_apply(const int* __restrict__ hist,
        const int* __restrict__ bsum, int* __restrict__ row_off,
        int* __restrict__ cursor, int n, int E) {
    const int t = threadIdx.x;
    const int i0 = blockIdx.x * 512 + t * 2;
    const int v0 = (i0 < n) ? hist[i0] : 0;
    const int v1 = (i0 + 1 < n) ? hist[i0 + 1] : 0;
    const int s = v0 + v1;
    const int lane = t & 63, w = t >> 6;
    int inc = s;
    #pragma unroll
    for (int o = 1; o < 64; o <<= 1) { int u = __shfl_up(inc, o); if (lane >= o) inc += u; }
    __shared__ int wsum[4], woff[4];
    if (lane == 63) wsum[w] = inc;
    __syncthreads();
    if (t == 0) { int r = 0; for (int k = 0; k < 4; ++k) { woff[k] = r; r += wsum[k]; } }
    __syncthreads();
    const int ex = bsum[blockIdx.x] + woff[w] + (inc - s);
    if (i0 < n)     { row_off[i0] = ex;          cursor[i0] = ex; }
    if (i0 + 1 < n) { row_off[i0 + 1] = ex + v0; cursor[i0 + 1] = ex + v0; }
    if (blockIdx.x == 0 && t == 0) row_off[n] = E;
}

// ---- CSR fill ----
__global__ void k_fill(const int* __restrict__ src, const int* __restrict__ dst,
                       int* __restrict__ cursor, int* __restrict__ csr, int E) {
    int e = blockIdx.x * blockDim.x + threadIdx.x;
    if (e < E) {
        int p = atomicAdd(&cursor[dst[e]], 1);
        csr[p] = src[e];
    }
}

// ---- fused SAGE layer: pull-mean (CSR) + dual GEMM + bias + ReLU (+ row L2 norm) ----
// 256 threads; 4 waves. Pull: wave w aggregates rows w*8..w*8+7 into hn LDS tile.
// GEMM: thread = (rh,col); 16 rows x 1 col each.
template<bool NORM>
__global__ __launch_bounds__(256) void k_sage(
    const float* __restrict__ h, const int* __restrict__ csr, const int* __restrict__ row_off,
    const float* __restrict__ Wself, const float* __restrict__ Wneigh,
    const float* __restrict__ bias, float* __restrict__ out, int n)
{
    __shared__ float hs[BM][D];
    __shared__ float hn[BM][D];
    const int row0 = blockIdx.x * BM;
    const int tid = threadIdx.x;
    const int lane = tid & 63;
    const int w = tid >> 6;

    // stage self tile (coalesced float4)
    #pragma unroll
    for (int i = 0; i < 4; ++i) {
        int f = tid + i * 256;
        int r = f >> 5, c4 = f & 31;
        int g = row0 + r;
        float4 v = make_float4(0.f, 0.f, 0.f, 0.f);
        if (g < n) v = *reinterpret_cast<const float4*>(h + (size_t)g * D + c4 * 4);
        *reinterpret_cast<float4*>(&hs[r][c4 * 4]) = v;
    }

    // pull neighbor means straight into LDS: wave w owns rows w*8..w*8+7
    #pragma unroll 1
    for (int rr = 0; rr < 8; ++rr) {
        const int r = w * 8 + rr;
        const int g = row0 + r;
        int beg = 0, end = 0;
        if (g < n) { beg = row_off[g]; end = row_off[g + 1]; }
        float2 a0 = make_float2(0.f, 0.f), a1 = make_float2(0.f, 0.f);
        int i = beg;
        for (; i + 1 < end; i += 2) {
            int s0 = csr[i], s1 = csr[i + 1];
            float2 v0 = *reinterpret_cast<const float2*>(h + (size_t)s0 * D + lane * 2);
            float2 v1 = *reinterpret_cast<const float2*>(h + (size_t)s1 * D + lane * 2);
            a0.x += v0.x; a0.y += v0.y;
            a1.x += v1.x; a1.y += v1.y;
        }
        if (i < end) {
            int s0 = csr[i];
            float2 v0 = *reinterpret_cast<const float2*>(h + (size_t)s0 * D + lane * 2);
            a0.x += v0.x; a0.y += v0.y;
        }
        const float invd = (end > beg) ? 1.0f / (float)(end - beg) : 0.0f;
        float2 rv;
        rv.x = (a0.x + a1.x) * invd;
        rv.y = (a0.y + a1.y) * invd;
        *reinterpret_cast<float2*>(&hn[r][lane * 2]) = rv;
    }
    __syncthreads();

    // dual GEMM
    const int col = tid & 127;
    const int rh = tid >> 7;
    float acc[16];
    #pragma unroll
    for (int r = 0; r < 16; ++r) acc[r] = 0.f;

    #pragma unroll 1
    for (int k4 = 0; k4 < 32; ++k4) {
        const int k = k4 * 4;
        const float ws0 = Wself[(k + 0) * D + col];
        const float ws1 = Wself[(k + 1) * D + col];
        const float ws2 = Wself[(k + 2) * D + col];
        const float ws3 = Wself[(k + 3) * D + col];
        const float wn0 = Wneigh[(k + 0) * D + col];
        const float wn1 = Wneigh[(k + 1) * D + col];
        const float wn2 = Wneigh[(k + 2) * D + col];
        const float wn3 = Wneigh[(k + 3) * D + col];
        #pragma unroll
        for (int r = 0; r < 16; ++r) {
            const float4 hv = *reinterpret_cast<const float4*>(&hs[rh * 16 + r][k]);
            const float4 nv = *reinterpret_cast<const float4*>(&hn[rh * 16 + r][k]);
            float t0 = fmaf(hv.x, ws0, acc[r]);
            t0 = fmaf(hv.y, ws1, t0);
            t0 = fmaf(hv.z, ws2, t0);
            t0 = fmaf(hv.w, ws3, t0);
            t0 = fmaf(nv.x, wn0, t0);
            t0 = fmaf(nv.y, wn1, t0);
            t0 = fmaf(nv.z, wn2, t0);
            t0 = fmaf(nv.w, wn3, t0);
            acc[r] = t0;
        }
    }

    const float bj = bias[col];
    if (!NORM) {
        #pragma unroll
        for (int r = 0; r < 16; ++r) {
            const int g = row0 + rh * 16 + r;
            if (g < n) out[(size_t)g * D + col] = fmaxf(acc[r] + bj, 0.f);
        }
    } else {
        // RACE FIX: all threads must finish reading hs/hn as GEMM inputs
        // before we overwrite hs with the relu output.
        __syncthreads();
        #pragma unroll
        for (int r = 0; r < 16; ++r) hs[rh * 16 + r][col] = fmaxf(acc[r] + bj, 0.f);
        __syncthreads();
        const int row = tid >> 3;          // 32 rows x 8 threads/row
        const int ci = (tid & 7) * 16;     // 16 cols per thread
        float ssq = 0.f;
        #pragma unroll
        for (int c = 0; c < 16; c += 4) {
            float4 v = *reinterpret_cast<float4*>(&hs[row][ci + c]);
            ssq += v.x * v.x + v.y * v.y + v.z * v.z + v.w * v.w;
        }
        #pragma unroll
        for (int o = 1; o < 8; o <<= 1) ssq += __shfl_xor(ssq, o);
        const float scale = 1.0f / fmaxf(sqrtf(ssq), 1e-12f);
        const int g = row0 + row;
        if (g < n) {
            #pragma unroll
            for (int c = 0; c < 16; c += 4) {
                float4 v = *reinterpret_cast<float4*>(&hs[row][ci + c]);
                v.x *= scale; v.y *= scale; v.z *= scale; v.w *= scale;
                *reinterpret_cast<float4*>(out + (size_t)g * D + ci + c) = v;
            }
        }
    }
}

extern "C" void kernel_launch(void* const* d_in, const int* in_sizes, int n_in,
                              void* d_out, int out_size, void* d_ws, size_t ws_size,
                              hipStream_t stream) {
    const float* x   = (const float*)d_in[0];
    const int*   src = (const int*)d_in[1];
    const int*   dst = (const int*)d_in[2];
    const float* Ws0 = (const float*)d_in[3];
    const float* Wn0 = (const float*)d_in[4];
    const float* b0  = (const float*)d_in[5];
    const float* Ws1 = (const float*)d_in[6];
    const float* Wn1 = (const float*)d_in[7];
    const float* b1  = (const float*)d_in[8];
    float* out = (float*)d_out;
    const int E = in_sizes[1];

    // workspace layout
    float* h1      = (float*)d_ws;                   // NN*D floats = 25.6 MB
    int*   hist    = (int*)(h1 + (size_t)NN * D);    // NN
    int*   bsum    = hist + NN;                      // 128
    int*   row_off = bsum + 128;                     // NN+1
    int*   cursor  = row_off + NN + 1;               // NN
    int*   csr     = cursor + NN;                    // E

    const int nb = (NN + 511) / 512;                 // 98 scan blocks

    // ---- build CSR ----
    hipMemsetAsync(hist, 0, (size_t)NN * sizeof(int), stream);
    k_hist<<<(E + 255) / 256, 256, 0, stream>>>(dst, hist, E);
    k_bsum<<<nb, 256, 0, stream>>>(hist, bsum, NN);
    k_bscan<<<1, 128, 0, stream>>>(bsum, nb);
    k_apply<<<nb, 256, 0, stream>>>(hist, bsum, row_off, cursor, NN, E);
    k_fill<<<(E + 255) / 256, 256, 0, stream>>>(src, dst, cursor, csr, E);

    // ---- layer 1: x -> h1 (workspace) ----
    k_sage<false><<<(NN + BM - 1) / BM, 256, 0, stream>>>(x, csr, row_off, Ws0, Wn0, b0, h1, NN);

    // ---- layer 2 + fused normalize: h1 -> out ----
    k_sage<true><<<(NN + BM - 1) / BM, 256, 0, stream>>>(h1, csr, row_off, Ws1, Wn1, b1, out, NN);
}

// Round 5
// 356.072 us; speedup vs baseline: 8.2434x; 1.2385x over previous
//
#include <hip/hip_runtime.h>

#define NN 50000
#define D 128
#define BM 32

// ---- in-degree histogram: one int atomic per edge ----
__global__ void k_hist(const int* __restrict__ dst, int* __restrict__ hist, int E) {
    int e = blockIdx.x * blockDim.x + threadIdx.x;
    if (e < E) atomicAdd(&hist[dst[e]], 1);
}

// ---- scan phase A: per-block (512 elems) partial sums ----
__global__ __launch_bounds__(256) void k_bsum(const int* __restrict__ hist,
                                              int* __restrict__ bsum, int n) {
    const int t = threadIdx.x;
    const int i0 = blockIdx.x * 512 + t * 2;
    int s = 0;
    if (i0 < n) s += hist[i0];
    if (i0 + 1 < n) s += hist[i0 + 1];
    #pragma unroll
    for (int o = 1; o < 64; o <<= 1) s += __shfl_xor(s, o);
    __shared__ int wsum[4];
    if ((t & 63) == 0) wsum[t >> 6] = s;
    __syncthreads();
    if (t == 0) bsum[blockIdx.x] = wsum[0] + wsum[1] + wsum[2] + wsum[3];
}

// ---- scan phase B: exclusive scan of <=128 block sums, one block ----
__global__ __launch_bounds__(128) void k_bscan(int* __restrict__ bsum, int nb) {
    const int t = threadIdx.x;
    const int lane = t & 63, w = t >> 6;
    int v = (t < nb) ? bsum[t] : 0;
    int inc = v;
    #pragma unroll
    for (int o = 1; o < 64; o <<= 1) { int u = __shfl_up(inc, o); if (lane >= o) inc += u; }
    __shared__ int wsum[2];
    if (lane == 63) wsum[w] = inc;
    __syncthreads();
    int off = (w == 1) ? wsum[0] : 0;
    if (t < nb) bsum[t] = off + inc - v;   // exclusive
}

// ---- scan phase C: in-block exclusive scan + block offset -> row_off, cursor ----
__global__ __launch_bounds__(256) void k_apply(const int* __restrict__ hist,
        const int* __restrict__ bsum, int* __restrict__ row_off,
        int* __restrict__ cursor, int n, int E) {
    const int t = threadIdx.x;
    const int i0 = blockIdx.x * 512 + t * 2;
    const int v0 = (i0 < n) ? hist[i0] : 0;
    const int v1 = (i0 + 1 < n) ? hist[i0 + 1] : 0;
    const int s = v0 + v1;
    const int lane = t & 63, w = t >> 6;
    int inc = s;
    #pragma unroll
    for (int o = 1; o < 64; o <<= 1) { int u = __shfl_up(inc, o); if (lane >= o) inc += u; }
    __shared__ int wsum[4], woff[4];
    if (lane == 63) wsum[w] = inc;
    __syncthreads();
    if (t == 0) { int r = 0; for (int k = 0; k < 4; ++k) { woff[k] = r; r += wsum[k]; } }
    __syncthreads();
    const int ex = bsum[blockIdx.x] + woff[w] + (inc - s);
    if (i0 < n)     { row_off[i0] = ex;          cursor[i0] = ex; }
    if (i0 + 1 < n) { row_off[i0 + 1] = ex + v0; cursor[i0 + 1] = ex + v0; }
    if (blockIdx.x == 0 && t == 0) row_off[n] = E;
}

// ---- CSR fill ----
__global__ void k_fill(const int* __restrict__ src, const int* __restrict__ dst,
                       int* __restrict__ cursor, int* __restrict__ csr, int E) {
    int e = blockIdx.x * blockDim.x + threadIdx.x;
    if (e < E) {
        int p = atomicAdd(&cursor[dst[e]], 1);
        csr[p] = src[e];
    }
}

// ---- fused SAGE layer: pull-mean (CSR) + dual GEMM + bias + ReLU (+ row L2 norm) ----
// 256 threads; 4 waves.
// Pull: each 16-lane quarter-wave owns one row at a time (lane = 8 floats = 32B),
//       4 rows in flight per wave -> ~16 outstanding dwordx4 loads per wave.
// GEMM: thread = (rh,col); 16 rows x 1 col each.
template<bool NORM>
__global__ __launch_bounds__(256) void k_sage(
    const float* __restrict__ h, const int* __restrict__ csr, const int* __restrict__ row_off,
    const float* __restrict__ Wself, const float* __restrict__ Wneigh,
    const float* __restrict__ bias, float* __restrict__ out, int n)
{
    __shared__ float hs[BM][D];
    __shared__ float hn[BM][D];
    const int row0 = blockIdx.x * BM;
    const int tid = threadIdx.x;
    const int lane = tid & 63;
    const int w = tid >> 6;

    // stage self tile (coalesced float4)
    #pragma unroll
    for (int i = 0; i < 4; ++i) {
        int f = tid + i * 256;
        int r = f >> 5, c4 = f & 31;
        int g = row0 + r;
        float4 v = make_float4(0.f, 0.f, 0.f, 0.f);
        if (g < n) v = *reinterpret_cast<const float4*>(h + (size_t)g * D + c4 * 4);
        *reinterpret_cast<float4*>(&hs[r][c4 * 4]) = v;
    }

    // pull neighbor means into LDS: quarter-wave q of wave w owns rows w*8+rr*4+q
    const int q  = lane >> 4;   // quarter id 0..3
    const int ql = lane & 15;   // lane within quarter; covers cols ql*8..ql*8+7
    #pragma unroll
    for (int rr = 0; rr < 2; ++rr) {
        const int r = w * 8 + rr * 4 + q;
        const int g = row0 + r;
        int beg = 0, end = 0;
        if (g < n) { beg = row_off[g]; end = row_off[g + 1]; }
        float4 a0 = make_float4(0.f, 0.f, 0.f, 0.f);
        float4 b0 = make_float4(0.f, 0.f, 0.f, 0.f);
        float4 a1 = make_float4(0.f, 0.f, 0.f, 0.f);
        float4 b1 = make_float4(0.f, 0.f, 0.f, 0.f);
        int i = beg;
        for (; i + 1 < end; i += 2) {
            const int s0 = csr[i], s1 = csr[i + 1];
            const float4* p0 = reinterpret_cast<const float4*>(h + (size_t)s0 * D + ql * 8);
            const float4* p1 = reinterpret_cast<const float4*>(h + (size_t)s1 * D + ql * 8);
            const float4 v0a = p0[0], v0b = p0[1];
            const float4 v1a = p1[0], v1b = p1[1];
            a0.x += v0a.x; a0.y += v0a.y; a0.z += v0a.z; a0.w += v0a.w;
            b0.x += v0b.x; b0.y += v0b.y; b0.z += v0b.z; b0.w += v0b.w;
            a1.x += v1a.x; a1.y += v1a.y; a1.z += v1a.z; a1.w += v1a.w;
            b1.x += v1b.x; b1.y += v1b.y; b1.z += v1b.z; b1.w += v1b.w;
        }
        if (i < end) {
            const int s0 = csr[i];
            const float4* p0 = reinterpret_cast<const float4*>(h + (size_t)s0 * D + ql * 8);
            const float4 v0a = p0[0], v0b = p0[1];
            a0.x += v0a.x; a0.y += v0a.y; a0.z += v0a.z; a0.w += v0a.w;
            b0.x += v0b.x; b0.y += v0b.y; b0.z += v0b.z; b0.w += v0b.w;
        }
        const float invd = (end > beg) ? 1.0f / (float)(end - beg) : 0.0f;
        float4 ra, rb;
        ra.x = (a0.x + a1.x) * invd; ra.y = (a0.y + a1.y) * invd;
        ra.z = (a0.z + a1.z) * invd; ra.w = (a0.w + a1.w) * invd;
        rb.x = (b0.x + b1.x) * invd; rb.y = (b0.y + b1.y) * invd;
        rb.z = (b0.z + b1.z) * invd; rb.w = (b0.w + b1.w) * invd;
        *reinterpret_cast<float4*>(&hn[r][ql * 8])     = ra;
        *reinterpret_cast<float4*>(&hn[r][ql * 8 + 4]) = rb;
    }
    __syncthreads();

    // dual GEMM
    const int col = tid & 127;
    const int rh = tid >> 7;
    float acc[16];
    #pragma unroll
    for (int r = 0; r < 16; ++r) acc[r] = 0.f;

    #pragma unroll 1
    for (int k4 = 0; k4 < 32; ++k4) {
        const int k = k4 * 4;
        const float ws0 = Wself[(k + 0) * D + col];
        const float ws1 = Wself[(k + 1) * D + col];
        const float ws2 = Wself[(k + 2) * D + col];
        const float ws3 = Wself[(k + 3) * D + col];
        const float wn0 = Wneigh[(k + 0) * D + col];
        const float wn1 = Wneigh[(k + 1) * D + col];
        const float wn2 = Wneigh[(k + 2) * D + col];
        const float wn3 = Wneigh[(k + 3) * D + col];
        #pragma unroll
        for (int r = 0; r < 16; ++r) {
            const float4 hv = *reinterpret_cast<const float4*>(&hs[rh * 16 + r][k]);
            const float4 nv = *reinterpret_cast<const float4*>(&hn[rh * 16 + r][k]);
            float t0 = fmaf(hv.x, ws0, acc[r]);
            t0 = fmaf(hv.y, ws1, t0);
            t0 = fmaf(hv.z, ws2, t0);
            t0 = fmaf(hv.w, ws3, t0);
            t0 = fmaf(nv.x, wn0, t0);
            t0 = fmaf(nv.y, wn1, t0);
            t0 = fmaf(nv.z, wn2, t0);
            t0 = fmaf(nv.w, wn3, t0);
            acc[r] = t0;
        }
    }

    const float bj = bias[col];
    if (!NORM) {
        #pragma unroll
        for (int r = 0; r < 16; ++r) {
            const int g = row0 + rh * 16 + r;
            if (g < n) out[(size_t)g * D + col] = fmaxf(acc[r] + bj, 0.f);
        }
    } else {
        // all threads must finish reading hs/hn as GEMM inputs before reuse
        __syncthreads();
        #pragma unroll
        for (int r = 0; r < 16; ++r) hs[rh * 16 + r][col] = fmaxf(acc[r] + bj, 0.f);
        __syncthreads();
        const int row = tid >> 3;          // 32 rows x 8 threads/row
        const int ci = (tid & 7) * 16;     // 16 cols per thread
        float ssq = 0.f;
        #pragma unroll
        for (int c = 0; c < 16; c += 4) {
            float4 v = *reinterpret_cast<float4*>(&hs[row][ci + c]);
            ssq += v.x * v.x + v.y * v.y + v.z * v.z + v.w * v.w;
        }
        #pragma unroll
        for (int o = 1; o < 8; o <<= 1) ssq += __shfl_xor(ssq, o);
        const float scale = 1.0f / fmaxf(sqrtf(ssq), 1e-12f);
        const int g = row0 + row;
        if (g < n) {
            #pragma unroll
            for (int c = 0; c < 16; c += 4) {
                float4 v = *reinterpret_cast<float4*>(&hs[row][ci + c]);
                v.x *= scale; v.y *= scale; v.z *= scale; v.w *= scale;
                *reinterpret_cast<float4*>(out + (size_t)g * D + ci + c) = v;
            }
        }
    }
}

extern "C" void kernel_launch(void* const* d_in, const int* in_sizes, int n_in,
                              void* d_out, int out_size, void* d_ws, size_t ws_size,
                              hipStream_t stream) {
    const float* x   = (const float*)d_in[0];
    const int*   src = (const int*)d_in[1];
    const int*   dst = (const int*)d_in[2];
    const float* Ws0 = (const float*)d_in[3];
    const float* Wn0 = (const float*)d_in[4];
    const float* b0  = (const float*)d_in[5];
    const float* Ws1 = (const float*)d_in[6];
    const float* Wn1 = (const float*)d_in[7];
    const float* b1  = (const float*)d_in[8];
    float* out = (float*)d_out;
    const int E = in_sizes[1];

    // workspace layout
    float* h1      = (float*)d_ws;                   // NN*D floats = 25.6 MB
    int*   hist    = (int*)(h1 + (size_t)NN * D);    // NN
    int*   bsum    = hist + NN;                      // 128
    int*   row_off = bsum + 128;                     // NN+1
    int*   cursor  = row_off + NN + 1;               // NN
    int*   csr     = cursor + NN;                    // E

    const int nb = (NN + 511) / 512;                 // 98 scan blocks

    // ---- build CSR ----
    hipMemsetAsync(hist, 0, (size_t)NN * sizeof(int), stream);
    k_hist<<<(E + 255) / 256, 256, 0, stream>>>(dst, hist, E);
    k_bsum<<<nb, 256, 0, stream>>>(hist, bsum, NN);
    k_bscan<<<1, 128, 0, stream>>>(bsum, nb);
    k_apply<<<nb, 256, 0, stream>>>(hist, bsum, row_off, cursor, NN, E);
    k_fill<<<(E + 255) / 256, 256, 0, stream>>>(src, dst, cursor, csr, E);

    // ---- layer 1: x -> h1 (workspace) ----
    k_sage<false><<<(NN + BM - 1) / BM, 256, 0, stream>>>(x, csr, row_off, Ws0, Wn0, b0, h1, NN);

    // ---- layer 2 + fused normalize: h1 -> out ----
    k_sage<true><<<(NN + BM - 1) / BM, 256, 0, stream>>>(h1, csr, row_off, Ws1, Wn1, b1, out, NN);
}

// Round 6
// 308.039 us; speedup vs baseline: 9.5289x; 1.1559x over previous
//
#include <hip/hip_runtime.h>

#define NN 50000
#define D 128
#define BM 32

typedef unsigned int uint;
typedef unsigned short ushort;

static __device__ __forceinline__ ushort f2bf(float f) {
    uint u = __float_as_uint(f);
    u = (u + 0x7FFFu + ((u >> 16) & 1u)) >> 16;   // RNE
    return (ushort)u;
}

// unpack-accumulate 8 bf16 (one uint4) into a[8]
#define ADD8(a, u)                                                  \
    {                                                               \
        a[0] += __uint_as_float((u).x << 16);                       \
        a[1] += __uint_as_float((u).x & 0xFFFF0000u);               \
        a[2] += __uint_as_float((u).y << 16);                       \
        a[3] += __uint_as_float((u).y & 0xFFFF0000u);               \
        a[4] += __uint_as_float((u).z << 16);                       \
        a[5] += __uint_as_float((u).z & 0xFFFF0000u);               \
        a[6] += __uint_as_float((u).w << 16);                       \
        a[7] += __uint_as_float((u).w & 0xFFFF0000u);               \
    }

// ---- fp32 -> bf16 mirror (8 elems/thread) ----
__global__ void k_cvt(const float* __restrict__ x, ushort* __restrict__ xb, int n8) {
    int t = blockIdx.x * blockDim.x + threadIdx.x;
    if (t >= n8) return;
    const float4* p = reinterpret_cast<const float4*>(x) + (size_t)t * 2;
    const float4 v0 = p[0], v1 = p[1];
    uint4 u;
    u.x = (uint)f2bf(v0.x) | ((uint)f2bf(v0.y) << 16);
    u.y = (uint)f2bf(v0.z) | ((uint)f2bf(v0.w) << 16);
    u.z = (uint)f2bf(v1.x) | ((uint)f2bf(v1.y) << 16);
    u.w = (uint)f2bf(v1.z) | ((uint)f2bf(v1.w) << 16);
    reinterpret_cast<uint4*>(xb)[t] = u;
}

// ---- in-degree histogram ----
__global__ void k_hist(const int* __restrict__ dst, int* __restrict__ hist, int E) {
    int e = blockIdx.x * blockDim.x + threadIdx.x;
    if (e < E) atomicAdd(&hist[dst[e]], 1);
}

// ---- scan phase A: per-block (512 elems) partial sums ----
__global__ __launch_bounds__(256) void k_bsum(const int* __restrict__ hist,
                                              int* __restrict__ bsum, int n) {
    const int t = threadIdx.x;
    const int i0 = blockIdx.x * 512 + t * 2;
    int s = 0;
    if (i0 < n) s += hist[i0];
    if (i0 + 1 < n) s += hist[i0 + 1];
    #pragma unroll
    for (int o = 1; o < 64; o <<= 1) s += __shfl_xor(s, o);
    __shared__ int wsum[4];
    if ((t & 63) == 0) wsum[t >> 6] = s;
    __syncthreads();
    if (t == 0) bsum[blockIdx.x] = wsum[0] + wsum[1] + wsum[2] + wsum[3];
}

// ---- scan phase B ----
__global__ __launch_bounds__(128) void k_bscan(int* __restrict__ bsum, int nb) {
    const int t = threadIdx.x;
    const int lane = t & 63, w = t >> 6;
    int v = (t < nb) ? bsum[t] : 0;
    int inc = v;
    #pragma unroll
    for (int o = 1; o < 64; o <<= 1) { int u = __shfl_up(inc, o); if (lane >= o) inc += u; }
    __shared__ int wsum[2];
    if (lane == 63) wsum[w] = inc;
    __syncthreads();
    int off = (w == 1) ? wsum[0] : 0;
    if (t < nb) bsum[t] = off + inc - v;   // exclusive
}

// ---- scan phase C ----
__global__ __launch_bounds__(256) void k_apply(const int* __restrict__ hist,
        const int* __restrict__ bsum, int* __restrict__ row_off,
        int* __restrict__ cursor, int n, int E) {
    const int t = threadIdx.x;
    const int i0 = blockIdx.x * 512 + t * 2;
    const int v0 = (i0 < n) ? hist[i0] : 0;
    const int v1 = (i0 + 1 < n) ? hist[i0 + 1] : 0;
    const int s = v0 + v1;
    const int lane = t & 63, w = t >> 6;
    int inc = s;
    #pragma unroll
    for (int o = 1; o < 64; o <<= 1) { int u = __shfl_up(inc, o); if (lane >= o) inc += u; }
    __shared__ int wsum[4], woff[4];
    if (lane == 63) wsum[w] = inc;
    __syncthreads();
    if (t == 0) { int r = 0; for (int k = 0; k < 4; ++k) { woff[k] = r; r += wsum[k]; } }
    __syncthreads();
    const int ex = bsum[blockIdx.x] + woff[w] + (inc - s);
    if (i0 < n)     { row_off[i0] = ex;          cursor[i0] = ex; }
    if (i0 + 1 < n) { row_off[i0 + 1] = ex + v0; cursor[i0 + 1] = ex + v0; }
    if (blockIdx.x == 0 && t == 0) row_off[n] = E;
}

// ---- CSR fill ----
__global__ void k_fill(const int* __restrict__ src, const int* __restrict__ dst,
                       int* __restrict__ cursor, int* __restrict__ csr, int E) {
    int e = blockIdx.x * blockDim.x + threadIdx.x;
    if (e < E) {
        int p = atomicAdd(&cursor[dst[e]], 1);
        csr[p] = src[e];
    }
}

// ---- fused SAGE layer ----
// Self tile: fp32 (layer 1, from x) or bf16 (layer 2, from h1b).
// Gather: always from bf16 mirror hb; one dwordx4 (8 bf16) per 16-lane quarter.
// GEMM fp32 from LDS; epilogue writes bf16 h1b (layer 1) or normalized fp32 out (layer 2).
template<bool NORM, bool BF16SELF>
__global__ __launch_bounds__(256) void k_sage(
    const float* __restrict__ hself, const ushort* __restrict__ hb,
    const int* __restrict__ csr, const int* __restrict__ row_off,
    const float* __restrict__ Wself, const float* __restrict__ Wneigh,
    const float* __restrict__ bias, ushort* __restrict__ outb,
    float* __restrict__ out, int n)
{
    __shared__ float hs[BM][D];
    __shared__ float hn[BM][D];
    const int row0 = blockIdx.x * BM;
    const int tid = threadIdx.x;
    const int lane = tid & 63;
    const int w = tid >> 6;

    // stage self tile
    if (!BF16SELF) {
        #pragma unroll
        for (int i = 0; i < 4; ++i) {
            int f = tid + i * 256;
            int r = f >> 5, c4 = f & 31;
            int g = row0 + r;
            float4 v = make_float4(0.f, 0.f, 0.f, 0.f);
            if (g < n) v = *reinterpret_cast<const float4*>(hself + (size_t)g * D + c4 * 4);
            *reinterpret_cast<float4*>(&hs[r][c4 * 4]) = v;
        }
    } else {
        const int r = tid >> 3;            // 32 rows, 8 threads/row
        const int c0 = (tid & 7) * 16;     // 16 bf16 each
        const int g = row0 + r;
        float a[16];
        #pragma unroll
        for (int j = 0; j < 16; ++j) a[j] = 0.f;
        if (g < n) {
            const uint4* p = reinterpret_cast<const uint4*>(hb + (size_t)g * D + c0);
            const uint4 u0 = p[0], u1 = p[1];
            float* alo = a;     ADD8(alo, u0);
            float* ahi = a + 8; ADD8(ahi, u1);
        }
        #pragma unroll
        for (int j = 0; j < 16; j += 4)
            *reinterpret_cast<float4*>(&hs[r][c0 + j]) = *reinterpret_cast<float4*>(&a[j]);
    }

    // pull neighbor means into LDS: quarter q of wave w owns rows w*8 + rr*4 + q
    const int q  = lane >> 4;
    const int ql = lane & 15;   // covers bf16 cols ql*8..ql*8+7
    #pragma unroll
    for (int rr = 0; rr < 2; ++rr) {
        const int r = w * 8 + rr * 4 + q;
        const int g = row0 + r;
        int beg = 0, end = 0;
        if (g < n) { beg = row_off[g]; end = row_off[g + 1]; }
        float a[8];
        #pragma unroll
        for (int j = 0; j < 8; ++j) a[j] = 0.f;
        int i = beg;
        for (; i + 3 < end; i += 4) {
            const int s0 = csr[i], s1 = csr[i + 1], s2 = csr[i + 2], s3 = csr[i + 3];
            const uint4 u0 = *reinterpret_cast<const uint4*>(hb + (size_t)s0 * D + ql * 8);
            const uint4 u1 = *reinterpret_cast<const uint4*>(hb + (size_t)s1 * D + ql * 8);
            const uint4 u2 = *reinterpret_cast<const uint4*>(hb + (size_t)s2 * D + ql * 8);
            const uint4 u3 = *reinterpret_cast<const uint4*>(hb + (size_t)s3 * D + ql * 8);
            ADD8(a, u0); ADD8(a, u1); ADD8(a, u2); ADD8(a, u3);
        }
        for (; i < end; ++i) {
            const int s0 = csr[i];
            const uint4 u0 = *reinterpret_cast<const uint4*>(hb + (size_t)s0 * D + ql * 8);
            ADD8(a, u0);
        }
        const float invd = (end > beg) ? 1.0f / (float)(end - beg) : 0.0f;
        #pragma unroll
        for (int j = 0; j < 8; ++j) a[j] *= invd;
        *reinterpret_cast<float4*>(&hn[r][ql * 8])     = *reinterpret_cast<float4*>(&a[0]);
        *reinterpret_cast<float4*>(&hn[r][ql * 8 + 4]) = *reinterpret_cast<float4*>(&a[4]);
    }
    __syncthreads();

    // dual GEMM
    const int col = tid & 127;
    const int rh = tid >> 7;
    float acc[16];
    #pragma unroll
    for (int r = 0; r < 16; ++r) acc[r] = 0.f;

    #pragma unroll 1
    for (int k4 = 0; k4 < 32; ++k4) {
        const int k = k4 * 4;
        const float ws0 = Wself[(k + 0) * D + col];
        const float ws1 = Wself[(k + 1) * D + col];
        const float ws2 = Wself[(k + 2) * D + col];
        const float ws3 = Wself[(k + 3) * D + col];
        const float wn0 = Wneigh[(k + 0) * D + col];
        const float wn1 = Wneigh[(k + 1) * D + col];
        const float wn2 = Wneigh[(k + 2) * D + col];
        const float wn3 = Wneigh[(k + 3) * D + col];
        #pragma unroll
        for (int r = 0; r < 16; ++r) {
            const float4 hv = *reinterpret_cast<const float4*>(&hs[rh * 16 + r][k]);
            const float4 nv = *reinterpret_cast<const float4*>(&hn[rh * 16 + r][k]);
            float t0 = fmaf(hv.x, ws0, acc[r]);
            t0 = fmaf(hv.y, ws1, t0);
            t0 = fmaf(hv.z, ws2, t0);
            t0 = fmaf(hv.w, ws3, t0);
            t0 = fmaf(nv.x, wn0, t0);
            t0 = fmaf(nv.y, wn1, t0);
            t0 = fmaf(nv.z, wn2, t0);
            t0 = fmaf(nv.w, wn3, t0);
            acc[r] = t0;
        }
    }

    const float bj = bias[col];
    if (!NORM) {
        #pragma unroll
        for (int r = 0; r < 16; ++r) {
            const int g = row0 + rh * 16 + r;
            if (g < n) outb[(size_t)g * D + col] = f2bf(fmaxf(acc[r] + bj, 0.f));
        }
    } else {
        // all threads must finish reading hs/hn as GEMM inputs before reuse
        __syncthreads();
        #pragma unroll
        for (int r = 0; r < 16; ++r) hs[rh * 16 + r][col] = fmaxf(acc[r] + bj, 0.f);
        __syncthreads();
        const int row = tid >> 3;
        const int ci = (tid & 7) * 16;
        float ssq = 0.f;
        #pragma unroll
        for (int c = 0; c < 16; c += 4) {
            float4 v = *reinterpret_cast<float4*>(&hs[row][ci + c]);
            ssq += v.x * v.x + v.y * v.y + v.z * v.z + v.w * v.w;
        }
        #pragma unroll
        for (int o = 1; o < 8; o <<= 1) ssq += __shfl_xor(ssq, o);
        const float scale = 1.0f / fmaxf(sqrtf(ssq), 1e-12f);
        const int g = row0 + row;
        if (g < n) {
            #pragma unroll
            for (int c = 0; c < 16; c += 4) {
                float4 v = *reinterpret_cast<float4*>(&hs[row][ci + c]);
                v.x *= scale; v.y *= scale; v.z *= scale; v.w *= scale;
                *reinterpret_cast<float4*>(out + (size_t)g * D + ci + c) = v;
            }
        }
    }
}

extern "C" void kernel_launch(void* const* d_in, const int* in_sizes, int n_in,
                              void* d_out, int out_size, void* d_ws, size_t ws_size,
                              hipStream_t stream) {
    const float* x   = (const float*)d_in[0];
    const int*   src = (const int*)d_in[1];
    const int*   dst = (const int*)d_in[2];
    const float* Ws0 = (const float*)d_in[3];
    const float* Wn0 = (const float*)d_in[4];
    const float* b0  = (const float*)d_in[5];
    const float* Ws1 = (const float*)d_in[6];
    const float* Wn1 = (const float*)d_in[7];
    const float* b1  = (const float*)d_in[8];
    float* out = (float*)d_out;
    const int E = in_sizes[1];

    // workspace layout (~29.4 MB)
    ushort* xb     = (ushort*)d_ws;                      // NN*D bf16 = 12.8 MB
    ushort* h1b    = xb + (size_t)NN * D;                // NN*D bf16 = 12.8 MB
    int*    hist   = (int*)(h1b + (size_t)NN * D);       // NN
    int*    bsum   = hist + NN;                          // 128
    int*    row_off= bsum + 128;                         // NN+1
    int*    cursor = row_off + NN + 1;                   // NN
    int*    csr    = cursor + NN;                        // E

    const int nb = (NN + 511) / 512;

    // ---- bf16 mirror of x ----
    k_cvt<<<(NN * D / 8 + 255) / 256, 256, 0, stream>>>(x, xb, NN * D / 8);

    // ---- build CSR ----
    hipMemsetAsync(hist, 0, (size_t)NN * sizeof(int), stream);
    k_hist<<<(E + 255) / 256, 256, 0, stream>>>(dst, hist, E);
    k_bsum<<<nb, 256, 0, stream>>>(hist, bsum, NN);
    k_bscan<<<1, 128, 0, stream>>>(bsum, nb);
    k_apply<<<nb, 256, 0, stream>>>(hist, bsum, row_off, cursor, NN, E);
    k_fill<<<(E + 255) / 256, 256, 0, stream>>>(src, dst, cursor, csr, E);

    // ---- layer 1: self from fp32 x, gather from xb -> h1b (bf16) ----
    k_sage<false, false><<<(NN + BM - 1) / BM, 256, 0, stream>>>(
        x, xb, csr, row_off, Ws0, Wn0, b0, h1b, nullptr, NN);

    // ---- layer 2 + normalize: self+gather from h1b -> out (fp32) ----
    k_sage<true, true><<<(NN + BM - 1) / BM, 256, 0, stream>>>(
        nullptr, h1b, csr, row_off, Ws1, Wn1, b1, nullptr, out, NN);
}